// Round 1
// baseline (67.621 us; speedup 1.0000x reference)
//
#include <hip/hip_runtime.h>
#include <hip/hip_bf16.h>

// LNS linear layer == x @ W^T + bias in exact arithmetic (LNS log/exp round-trip
// only adds ~1e-6 relative noise). Computed as bf16-MFMA GEMM-NT, fp32 accumulate.
// Sizes fixed by setup_inputs: B = K = N = 512.

typedef __bf16 bf16x8 __attribute__((ext_vector_type(8)));
typedef float floatx16 __attribute__((ext_vector_type(16)));

constexpr int Bdim = 512;  // batch rows
constexpr int Kdim = 512;  // in_features
constexpr int Ndim = 512;  // out_features

// Pack 8 fp32 -> 8 bf16 (RNE) using the packed converter (v_cvt_pk_bf16_f32).
__device__ __forceinline__ bf16x8 cvt8(float4 a, float4 b) {
    union { bf16x8 v; __hip_bfloat162 h[4]; } u;
    u.h[0] = __float22bfloat162_rn(float2{a.x, a.y});
    u.h[1] = __float22bfloat162_rn(float2{a.z, a.w});
    u.h[2] = __float22bfloat162_rn(float2{b.x, b.y});
    u.h[3] = __float22bfloat162_rn(float2{b.z, b.w});
    return u.v;
}

// One wave per block; each wave owns a 32x32 C tile, full K.
// A-operand lane map (32x32x16 bf16): row = lane&31, k = (lane>>5)*8 + j
// B-operand lane map:                 col = lane&31, k = (lane>>5)*8 + j
//   -> both fragments are 8 contiguous k-elements of a K-contiguous row (x row / w row).
// C/D lane map: col = lane&31, row = (reg&3) + 8*(reg>>2) + 4*(lane>>5)   [m74/m101]
__global__ __launch_bounds__(64) void lns_linear_mfma(
    const float* __restrict__ x,      // [B, K]
    const float* __restrict__ w,      // [N, K]
    const float* __restrict__ bias,   // [N]
    float* __restrict__ out)          // [B, N]
{
    const int lane = threadIdx.x;          // 0..63
    const int m0 = blockIdx.y * 32;
    const int n0 = blockIdx.x * 32;
    const int r  = lane & 31;
    const int kq = (lane >> 5) * 8;        // 0 or 8

    const float* xrow = x + (size_t)(m0 + r) * Kdim + kq;
    const float* wrow = w + (size_t)(n0 + r) * Kdim + kq;

    floatx16 acc;
#pragma unroll
    for (int i = 0; i < 16; ++i) acc[i] = 0.0f;

#pragma unroll 4
    for (int k = 0; k < Kdim; k += 16) {
        float4 a0 = *reinterpret_cast<const float4*>(xrow + k);
        float4 a1 = *reinterpret_cast<const float4*>(xrow + k + 4);
        float4 b0 = *reinterpret_cast<const float4*>(wrow + k);
        float4 b1 = *reinterpret_cast<const float4*>(wrow + k + 4);
        bf16x8 af = cvt8(a0, a1);
        bf16x8 bf = cvt8(b0, b1);
        acc = __builtin_amdgcn_mfma_f32_32x32x16_bf16(af, bf, acc, 0, 0, 0);
    }

    // Epilogue: bias add (bias col = lane&31, constant per lane) + store.
    const float bv = bias[n0 + r];
    const int rbase = (lane >> 5) * 4;
#pragma unroll
    for (int reg = 0; reg < 16; ++reg) {
        const int row = (reg & 3) + 8 * (reg >> 2) + rbase;
        out[(size_t)(m0 + row) * Ndim + (n0 + r)] = acc[reg] + bv;
    }
}

extern "C" void kernel_launch(void* const* d_in, const int* in_sizes, int n_in,
                              void* d_out, int out_size, void* d_ws, size_t ws_size,
                              hipStream_t stream) {
    const float* x    = (const float*)d_in[0];
    const float* w    = (const float*)d_in[1];
    const float* bias = (const float*)d_in[2];
    float* out = (float*)d_out;

    dim3 grid(Ndim / 32, Bdim / 32);   // 16 x 16 = 256 blocks, 1 wave each
    lns_linear_mfma<<<grid, 64, 0, stream>>>(x, w, bias, out);
}

// Round 2
// 61.159 us; speedup vs baseline: 1.1057x; 1.1057x over previous
//
#include <hip/hip_runtime.h>
#include <hip/hip_bf16.h>

// LNS linear == x @ W^T + bias exactly (log/exp round-trip is ~1e-6 rel noise).
// bf16 MFMA GEMM-NT, fp32 accumulate. B = K = N = 512.
//
// R2 structure: 256 blocks (one 32x32 C-tile each) x 4 waves, split-K in-block
// (each wave K=128 -> 8 MFMA), LDS reduction. Rationale: problem is tiny
// (268 MFLOP) and latency-bound; R1's 1-wave blocks left 3/4 SIMDs idle and
// serialized ~32 L2-latency exposures per wave. Full unroll lets the compiler
// hoist a wave's 32 dwordx4 loads ahead of one vmcnt wait.

typedef __bf16 bf16x8 __attribute__((ext_vector_type(8)));
typedef float floatx16 __attribute__((ext_vector_type(16)));

constexpr int Bdim = 512;  // batch rows
constexpr int Kdim = 512;  // in_features
constexpr int Ndim = 512;  // out_features

// Pack 8 fp32 -> 8 bf16 (RNE) via packed converter (v_cvt_pk_bf16_f32).
__device__ __forceinline__ bf16x8 cvt8(float4 a, float4 b) {
    union { bf16x8 v; __hip_bfloat162 h[4]; } u;
    u.h[0] = __float22bfloat162_rn(float2{a.x, a.y});
    u.h[1] = __float22bfloat162_rn(float2{a.z, a.w});
    u.h[2] = __float22bfloat162_rn(float2{b.x, b.y});
    u.h[3] = __float22bfloat162_rn(float2{b.z, b.w});
    return u.v;
}

// A/B operand lane map (32x32x16 bf16): row|col = lane&31, k = (lane>>5)*8 + j
// C/D lane map: col = lane&31, row = (reg&3) + 8*(reg>>2) + 4*(lane>>5)  [m74/m101]
__global__ __launch_bounds__(256, 1) void lns_linear_mfma(
    const float* __restrict__ x,      // [B, K]
    const float* __restrict__ w,      // [N, K]
    const float* __restrict__ bias,   // [N]
    float* __restrict__ out)          // [B, N]
{
    __shared__ float red[4 * 1024];   // 4 waves x 32x32 fp32 partials (16 KiB)

    const int tid  = threadIdx.x;
    const int wave = tid >> 6;        // 0..3 -> K slice
    const int lane = tid & 63;
    const int m0 = blockIdx.y * 32;
    const int n0 = blockIdx.x * 32;
    const int r  = lane & 31;
    const int kq = (lane >> 5) * 8;   // 0 or 8

    const float* xrow = x + (size_t)(m0 + r) * Kdim + wave * 128 + kq;
    const float* wrow = w + (size_t)(n0 + r) * Kdim + wave * 128 + kq;

    floatx16 acc;
#pragma unroll
    for (int i = 0; i < 16; ++i) acc[i] = 0.0f;

#pragma unroll
    for (int k = 0; k < 128; k += 16) {
        float4 a0 = *reinterpret_cast<const float4*>(xrow + k);
        float4 a1 = *reinterpret_cast<const float4*>(xrow + k + 4);
        float4 b0 = *reinterpret_cast<const float4*>(wrow + k);
        float4 b1 = *reinterpret_cast<const float4*>(wrow + k + 4);
        acc = __builtin_amdgcn_mfma_f32_32x32x16_bf16(cvt8(a0, a1), cvt8(b0, b1), acc, 0, 0, 0);
    }

    // Dump partials to LDS. Consecutive lane -> consecutive addr: 2-way bank
    // aliasing only (free on gfx950, m136).
#pragma unroll
    for (int reg = 0; reg < 16; ++reg)
        red[wave * 1024 + reg * 64 + lane] = acc[reg];
    __syncthreads();

    // 256 threads x 4 elements: sum 4 K-slices, add bias, store.
#pragma unroll
    for (int i = 0; i < 4; ++i) {
        const int idx = tid + i * 256;            // (reg, lane) flat index
        float s = red[idx] + red[1024 + idx] + red[2048 + idx] + red[3072 + idx];
        const int reg = idx >> 6;
        const int ln  = idx & 63;
        const int row = (reg & 3) + 8 * (reg >> 2) + 4 * (ln >> 5);
        const int col = ln & 31;
        out[(size_t)(m0 + row) * Ndim + (n0 + col)] = s + bias[n0 + col];
    }
}

extern "C" void kernel_launch(void* const* d_in, const int* in_sizes, int n_in,
                              void* d_out, int out_size, void* d_ws, size_t ws_size,
                              hipStream_t stream) {
    const float* x    = (const float*)d_in[0];
    const float* w    = (const float*)d_in[1];
    const float* bias = (const float*)d_in[2];
    float* out = (float*)d_out;

    dim3 grid(Ndim / 32, Bdim / 32);   // 16 x 16 = 256 blocks, 4 waves each
    lns_linear_mfma<<<grid, 256, 0, stream>>>(x, w, bias, out);
}

// Round 3
// 61.096 us; speedup vs baseline: 1.1068x; 1.0010x over previous
//
#include <hip/hip_runtime.h>
#include <hip/hip_bf16.h>

// LNS linear == x @ W^T + bias exactly (log/exp round-trip is ~1e-6 rel noise).
// bf16 MFMA GEMM-NT, fp32 accumulate. B = K = N = 512.
//
// Structure (R2): 256 blocks (one 32x32 C-tile) x 4 waves, in-block split-K
// (K=128/wave, 8-MFMA chain, loads fully hoisted ahead of one vmcnt wait),
// LDS reduction. R3: vectorized epilogue — the C/D lane map makes 4
// consecutive cols LDS-contiguous, so the reduce is 4x ds_read_b128 +
// 1x global_store_dwordx4 per thread instead of 16x b32 + 4x dword.
//
// Bench context: timed graph is dominated by the harness's 268 MB d_ws
// re-poison (~41 us at 82% HBM peak) + restores/gaps (~16 us); kernel is
// the remaining ~4 us. Inputs are L2-cold every iteration (poison evicts).

typedef __bf16 bf16x8 __attribute__((ext_vector_type(8)));
typedef float floatx16 __attribute__((ext_vector_type(16)));

constexpr int Bdim = 512;  // batch rows
constexpr int Kdim = 512;  // in_features
constexpr int Ndim = 512;  // out_features

// Pack 8 fp32 -> 8 bf16 (RNE) via packed converter (v_cvt_pk_bf16_f32).
__device__ __forceinline__ bf16x8 cvt8(float4 a, float4 b) {
    union { bf16x8 v; __hip_bfloat162 h[4]; } u;
    u.h[0] = __float22bfloat162_rn(float2{a.x, a.y});
    u.h[1] = __float22bfloat162_rn(float2{a.z, a.w});
    u.h[2] = __float22bfloat162_rn(float2{b.x, b.y});
    u.h[3] = __float22bfloat162_rn(float2{b.z, b.w});
    return u.v;
}

// A/B operand lane map (32x32x16 bf16): row|col = lane&31, k = (lane>>5)*8 + j
// C/D lane map: col = lane&31, row = (reg&3) + 8*(reg>>2) + 4*(lane>>5)  [m74/m101]
__global__ __launch_bounds__(256, 1) void lns_linear_mfma(
    const float* __restrict__ x,      // [B, K]
    const float* __restrict__ w,      // [N, K]
    const float* __restrict__ bias,   // [N]
    float* __restrict__ out)          // [B, N]
{
    __shared__ float red[4 * 1024];   // 4 waves x 32x32 fp32 partials (16 KiB)

    const int tid  = threadIdx.x;
    const int wave = tid >> 6;        // 0..3 -> K slice
    const int lane = tid & 63;
    const int m0 = blockIdx.y * 32;
    const int n0 = blockIdx.x * 32;
    const int r  = lane & 31;
    const int kq = (lane >> 5) * 8;   // 0 or 8

    const float* xrow = x + (size_t)(m0 + r) * Kdim + wave * 128 + kq;
    const float* wrow = w + (size_t)(n0 + r) * Kdim + wave * 128 + kq;

    floatx16 acc;
#pragma unroll
    for (int i = 0; i < 16; ++i) acc[i] = 0.0f;

#pragma unroll
    for (int k = 0; k < 128; k += 16) {
        float4 a0 = *reinterpret_cast<const float4*>(xrow + k);
        float4 a1 = *reinterpret_cast<const float4*>(xrow + k + 4);
        float4 b0 = *reinterpret_cast<const float4*>(wrow + k);
        float4 b1 = *reinterpret_cast<const float4*>(wrow + k + 4);
        acc = __builtin_amdgcn_mfma_f32_32x32x16_bf16(cvt8(a0, a1), cvt8(b0, b1), acc, 0, 0, 0);
    }

    // Dump partials: consecutive lane -> consecutive addr (2-way aliasing,
    // free per m136).
#pragma unroll
    for (int reg = 0; reg < 16; ++reg)
        red[wave * 1024 + reg * 64 + lane] = acc[reg];
    __syncthreads();

    // Vectorized reduce+store: thread t owns (row = t>>3, cols (t&7)*4..+3).
    // Inverse C/D map: ln = col + 32*((row>>2)&1), reg = (row&3) + 4*(row>>3)
    // -> 4 consecutive cols are contiguous in red => ds_read_b128 per slice.
    const int row = tid >> 3;
    const int c0  = (tid & 7) * 4;
    const int reg = (row & 3) + 4 * (row >> 3);
    const int base = reg * 64 + 32 * ((row >> 2) & 1) + c0;

    float4 s0 = *reinterpret_cast<const float4*>(&red[base]);
    float4 s1 = *reinterpret_cast<const float4*>(&red[1024 + base]);
    float4 s2 = *reinterpret_cast<const float4*>(&red[2048 + base]);
    float4 s3 = *reinterpret_cast<const float4*>(&red[3072 + base]);
    float4 bv = *reinterpret_cast<const float4*>(&bias[n0 + c0]);

    float4 o;
    o.x = s0.x + s1.x + s2.x + s3.x + bv.x;
    o.y = s0.y + s1.y + s2.y + s3.y + bv.y;
    o.z = s0.z + s1.z + s2.z + s3.z + bv.z;
    o.w = s0.w + s1.w + s2.w + s3.w + bv.w;

    *reinterpret_cast<float4*>(&out[(size_t)(m0 + row) * Ndim + (n0 + c0)]) = o;
}

extern "C" void kernel_launch(void* const* d_in, const int* in_sizes, int n_in,
                              void* d_out, int out_size, void* d_ws, size_t ws_size,
                              hipStream_t stream) {
    const float* x    = (const float*)d_in[0];
    const float* w    = (const float*)d_in[1];
    const float* bias = (const float*)d_in[2];
    float* out = (float*)d_out;

    dim3 grid(Ndim / 32, Bdim / 32);   // 16 x 16 = 256 blocks, 4 waves each
    lns_linear_mfma<<<grid, 256, 0, stream>>>(x, w, bias, out);
}